// Round 5
// baseline (386.675 us; speedup 1.0000x reference)
//
#include <hip/hip_runtime.h>
#include <hip/hip_bf16.h>

typedef __attribute__((ext_vector_type(8))) short bf16x8;
typedef __attribute__((ext_vector_type(4))) float f32x4;

#define MFMA16(a, b, c) __builtin_amdgcn_mfma_f32_16x16x32_bf16((a), (b), (c), 0, 0, 0)

typedef __attribute__((address_space(1))) const void gconst_t;
typedef __attribute__((address_space(3))) void lds_t;
__device__ __forceinline__ void gload16(const void* gp, void* lp) {
    __builtin_amdgcn_global_load_lds((gconst_t*)gp, (lds_t*)lp, 16, 0, 0);
}

#define BAR() asm volatile("s_barrier" ::: "memory")
#define VMCNT4() asm volatile("s_waitcnt vmcnt(4)" ::: "memory")
#define DRAIN() asm volatile("s_waitcnt vmcnt(0) lgkmcnt(0)" ::: "memory")
#define PRIO1() __builtin_amdgcn_s_setprio(1)
#define PRIO0() __builtin_amdgcn_s_setprio(0)
#define SCHED0() __builtin_amdgcn_sched_barrier(0)

// ---------------------------------------------------------------------------
// Transpose + cast fp32 -> bf16:  X tensors (R=2048, C=1024, z=4 batches),
// also writes the raw fp32 tile into the concat output's first 2048 channels.
// ---------------------------------------------------------------------------
__global__ void transpose_x(const float* __restrict__ in, __hip_bfloat16* __restrict__ out,
                            float* __restrict__ copy_out) {
    __shared__ float tile[32][33];
    int r0 = blockIdx.y * 32, c0 = blockIdx.x * 32;
    size_t zoff = (size_t)blockIdx.z * 2048 * 1024;
    const float* ib = in + zoff;
    __hip_bfloat16* ob = out + zoff;
    float* cb = copy_out + (size_t)blockIdx.z * 4194304;
    int tx = threadIdx.x, ty = threadIdx.y;
#pragma unroll
    for (int i = ty; i < 32; i += 8) {
        float v = ib[(size_t)(r0 + i) * 1024 + c0 + tx];
        tile[i][tx] = v;
        cb[(size_t)(r0 + i) * 1024 + c0 + tx] = v;
    }
    __syncthreads();
#pragma unroll
    for (int i = ty; i < 32; i += 8)
        ob[(size_t)(c0 + i) * 2048 + r0 + tx] = __float2bfloat16(tile[tx][i]);
}

// All four 2048x2048 weight transposes in one dispatch (z selects the matrix)
struct TArgs {
    const float* src[4];
    __hip_bfloat16* dst[4];
};
__global__ void transpose_w4(TArgs ta) {
    __shared__ float tile[32][33];
    const int z = blockIdx.z;
    const float* __restrict__ ib = ta.src[z];
    __hip_bfloat16* __restrict__ ob = ta.dst[z];
    int r0 = blockIdx.y * 32, c0 = blockIdx.x * 32;
    int tx = threadIdx.x, ty = threadIdx.y;
#pragma unroll
    for (int i = ty; i < 32; i += 8)
        tile[i][tx] = ib[(size_t)(r0 + i) * 2048 + c0 + tx];
    __syncthreads();
#pragma unroll
    for (int i = ty; i < 32; i += 8)
        ob[(size_t)(c0 + i) * 2048 + r0 + tx] = __float2bfloat16(tile[tx][i]);
}

// rel_emb (63x256 fp32) -> bf16 padded to 64 rows (row 63 = 0)
__global__ void conv_rel(const float* __restrict__ rel, __hip_bfloat16* __restrict__ relb) {
    int i = blockIdx.x * 256 + threadIdx.x;  // 64*256 = 16384
    if (i < 64 * 256) {
        int r = i >> 8;
        relb[i] = __float2bfloat16(r < 63 ? rel[i] : 0.f);
    }
}

// ---------------------------------------------------------------------------
// 256x256-tile, BK=64, 8-wave (2x4), 8-phase counted-vmcnt GEMM with
// REGISTER PING-PONG: phase body = [STAGE | (gate) | BAR | READS(p+1) | MFMA(p)].
// Reads for phase p+1 go to registers disjoint from MFMA(p)'s operands, so the
// LDS pipe (reads) and MFMA pipe overlap inside each barrier window.
// Sets: alo/ahi/bhi single-buffered (write/consume phases disjoint);
// blo double-buffered (consumed P4 while reloaded for P5).
// Safety: every read follows the barrier after the staging gate (vmcnt(4) at
// P4/P8); every re-stage is >=1 barrier after the region's last read
// completion (reads complete before the reader's MFMA < its barrier).
// ---------------------------------------------------------------------------
struct GArgs {
    const __hip_bfloat16* A[6];
    const __hip_bfloat16* B[6];
    void* C[6];
    const float* bias[6];
};

template <int MODE>
__global__ __launch_bounds__(512, 2) void gemm8p(GArgs ga, int N, int K,
                                                 float* __restrict__ dout) {
    __shared__ __align__(16) char smem[131072];

    // XCD-aware chunked swizzle (nwg % 8 == 0 for all our launches)
    const int gx = gridDim.x, gy = gridDim.y;
    int lid = blockIdx.x + gx * (blockIdx.y + gy * blockIdx.z);
    const int nwg = gx * gy * gridDim.z;
    int swz = (lid & 7) * (nwg >> 3) + (lid >> 3);
    const int z = swz / (gx * gy);
    int rem = swz - z * (gx * gy);
    const int by = rem / gx;
    const int bx = rem - by * gx;

    const __hip_bfloat16* __restrict__ A = ga.A[z];
    const __hip_bfloat16* __restrict__ B = ga.B[z];
    const float* __restrict__ bias = ga.bias[z];
    const int row0 = by * 256, col0 = bx * 256;

    const int tid = threadIdx.x;
    const int wave = tid >> 6, lane = tid & 63;
    const int l15 = lane & 15, lg = lane >> 4;
    const int wm = wave >> 2, wn = wave & 3;  // 2 x 4 wave grid

    // staging lane constants (source pre-swizzled, LDS dest linear)
    const int srow = tid >> 3;               // 0..63: row within 64-row chunk
    const int sch = (tid & 7) ^ (srow & 7);  // swizzled 16B chunk in row
    // ds_read lane constants
    const int xr = (l15 & 7) << 4;
    const int off0 = (lg * 16) ^ xr;       // ks=0 byte offset in 128B row
    const int off1 = (64 + lg * 16) ^ xr;  // ks=1
    const int arow = wm * 16384;                 // this wave's A half region
    const int brow = 32768 + (wn >> 1) * 16384;  // this wave's B half region
    const int bloc = (wn & 1) * 64;              // local row base in B half

    f32x4 acc[8][4] = {};
    bf16x8 alo[4][2], ahi[4][2], bhi[2][2], blo0[2][2], blo1[2][2];

    const int NT = K >> 6;   // K-tiles (32)
    const int NI = NT >> 1;  // iterations (16)

    auto STAGE = [&](const __hip_bfloat16* base, int rowb, int T, int bufc, int isB, int h) {
#pragma unroll
        for (int L = 0; L < 2; ++L) {
            const __hip_bfloat16* g =
                base + (size_t)(rowb + h * 128 + L * 64 + srow) * K + T * 64 + sch * 8;
            gload16(g, smem + bufc * 65536 + isB * 32768 + h * 16384 + L * 8192 + wave * 1024);
        }
    };
    auto LDA = [&](int bufc, int mf, int ks) {
        return *(const bf16x8*)(smem + bufc * 65536 + arow + (mf * 16 + l15) * 128 +
                                (ks ? off1 : off0));
    };
    auto LDB = [&](int bufc, int nf, int ks) {
        return *(const bf16x8*)(smem + bufc * 65536 + brow + (bloc + nf * 16 + l15) * 128 +
                                (ks ? off1 : off0));
    };

#define READ_ALO(BUF)                                  \
    _Pragma("unroll") for (int mf = 0; mf < 4; ++mf) { \
        alo[mf][0] = LDA(BUF, mf, 0);                  \
        alo[mf][1] = LDA(BUF, mf, 1);                  \
    }
#define READ_AHI(BUF)                                  \
    _Pragma("unroll") for (int mf = 0; mf < 4; ++mf) { \
        ahi[mf][0] = LDA(BUF, 4 + mf, 0);              \
        ahi[mf][1] = LDA(BUF, 4 + mf, 1);              \
    }
#define READ_BHI(BUF)                                  \
    _Pragma("unroll") for (int nf = 0; nf < 2; ++nf) { \
        bhi[nf][0] = LDB(BUF, 2 + nf, 0);              \
        bhi[nf][1] = LDB(BUF, 2 + nf, 1);              \
    }
#define READ_BLO(BUF, DST)                             \
    _Pragma("unroll") for (int nf = 0; nf < 2; ++nf) { \
        DST[nf][0] = LDB(BUF, nf, 0);                  \
        DST[nf][1] = LDB(BUF, nf, 1);                  \
    }
#define MQ(AR, MOFF, NOFF, BR)                                          \
    SCHED0();                                                           \
    PRIO1();                                                            \
    _Pragma("unroll") for (int mf = 0; mf < 4; ++mf)                    \
    _Pragma("unroll") for (int nf = 0; nf < 2; ++nf) {                  \
        acc[(MOFF) + mf][(NOFF) + nf] =                                 \
            MFMA16(AR[mf][0], BR[nf][0], acc[(MOFF) + mf][(NOFF) + nf]); \
        acc[(MOFF) + mf][(NOFF) + nf] =                                 \
            MFMA16(AR[mf][1], BR[nf][1], acc[(MOFF) + mf][(NOFF) + nf]); \
    }                                                                   \
    PRIO0();

    // prologue: tile0 complete, tile1 B0+A0 in flight; then pre-read P1 operands
    STAGE(B, col0, 0, 0, 1, 0);
    STAGE(A, row0, 0, 0, 0, 0);
    STAGE(A, row0, 0, 0, 0, 1);
    STAGE(B, col0, 0, 0, 1, 1);
    STAGE(B, col0, 1, 1, 1, 0);
    STAGE(A, row0, 1, 1, 0, 0);
    VMCNT4();
    BAR();
    READ_ALO(0);
    READ_BLO(0, blo0);

#pragma unroll 1
    for (int i = 0; i < NI; ++i) {
        const int t = 2 * i;
        const int T2 = (t + 2 < NT) ? t + 2 : t;      // tail: idempotent re-stage
        const int T3 = (t + 3 < NT) ? t + 3 : t + 1;  // (same parity, same data)
        // ---- tile t (buf0) ----
        STAGE(A, row0, t + 1, 1, 0, 1);  // P1
        BAR();
        READ_BHI(0);
        MQ(alo, 0, 0, blo0);

        STAGE(B, col0, t + 1, 1, 1, 1);  // P2
        BAR();
        READ_AHI(0);
        MQ(alo, 0, 2, bhi);

        STAGE(B, col0, T2, 0, 1, 0);  // P3
        BAR();
        MQ(ahi, 4, 2, bhi);

        STAGE(A, row0, T2, 0, 0, 0);  // P4
        VMCNT4();
        BAR();
        READ_ALO(1);
        READ_BLO(1, blo1);
        MQ(ahi, 4, 0, blo0);

        // ---- tile t+1 (buf1) ----
        STAGE(A, row0, T2, 0, 0, 1);  // P5
        BAR();
        READ_BHI(1);
        MQ(alo, 0, 0, blo1);

        STAGE(B, col0, T2, 0, 1, 1);  // P6
        BAR();
        READ_AHI(1);
        MQ(alo, 0, 2, bhi);

        STAGE(B, col0, T3, 1, 1, 0);  // P7
        BAR();
        MQ(ahi, 4, 2, bhi);

        STAGE(A, row0, T3, 1, 0, 0);  // P8
        VMCNT4();
        BAR();
        READ_ALO(0);
        READ_BLO(0, blo0);
        MQ(ahi, 4, 0, blo1);
    }
    DRAIN();  // drain tail stages + trailing reads before epilogue

    if (MODE == 0) {
        __hip_bfloat16* __restrict__ C = (__hip_bfloat16*)ga.C[z];
#pragma unroll
        for (int mf = 0; mf < 8; ++mf) {
            int m = row0 + wm * 128 + mf * 16 + lg * 4;
#pragma unroll
            for (int nf = 0; nf < 4; ++nf) {
                int n = col0 + wn * 64 + nf * 16 + l15;
                float bv = bias[n];
#pragma unroll
                for (int r = 0; r < 4; ++r)
                    C[(size_t)(m + r) * N + n] = __float2bfloat16(acc[mf][nf][r] + bv);
            }
        }
    } else {
        // rows = output channel n, cols = m = b*1024 + p (coalesced in p)
        float* __restrict__ OB = dout + (size_t)z * 16777216;
#pragma unroll
        for (int mf = 0; mf < 8; ++mf) {
            int n0 = row0 + wm * 128 + mf * 16 + lg * 4;
#pragma unroll
            for (int nf = 0; nf < 4; ++nf) {
                int m = col0 + wn * 64 + nf * 16 + l15;
                size_t base = (size_t)(m >> 10) * 4194304 + (size_t)(m & 1023);
#pragma unroll
                for (int r = 0; r < 4; ++r) {
                    int n = n0 + r;
                    OB[base + (size_t)(2048 + n) * 1024] = acc[mf][nf][r] + bias[n];
                }
            }
        }
    }
#undef READ_ALO
#undef READ_AHI
#undef READ_BHI
#undef READ_BLO
#undef MQ
}

// ---------------------------------------------------------------------------
// Axial attention: one block per (dir, b, head, w).  Q,K,V row-major [4096][2048] bf16.
// ---------------------------------------------------------------------------
__global__ __launch_bounds__(256, 2) void attn_kernel(
    const __hip_bfloat16* __restrict__ Qa, const __hip_bfloat16* __restrict__ Ka,
    const __hip_bfloat16* __restrict__ Va, const __hip_bfloat16* __restrict__ Qb,
    const __hip_bfloat16* __restrict__ Kb, const __hip_bfloat16* __restrict__ Vb,
    const __hip_bfloat16* __restrict__ relb, __hip_bfloat16* __restrict__ Oa,
    __hip_bfloat16* __restrict__ Ob) {
    const int w = blockIdx.x;   // 0..31
    const int nh = blockIdx.y;  // 0..7
    const int zb = blockIdx.z;  // dir*4 + b
    const int dir = zb >> 2, b = zb & 3;
    const __hip_bfloat16* __restrict__ Q = dir ? Qb : Qa;
    const __hip_bfloat16* __restrict__ K = dir ? Kb : Ka;
    const __hip_bfloat16* __restrict__ V = dir ? Vb : Va;
    __hip_bfloat16* __restrict__ O = dir ? Ob : Oa;

    __shared__ __align__(16) __hip_bfloat16 vt[256 * 40];  // V^T, stride 40
    __shared__ float ssc[32 * 32];
    __shared__ float es[32 * 64];
    __shared__ __align__(16) __hip_bfloat16 ps[32 * 32];

    const int tid = threadIdx.x;
    const int lane = tid & 63, wave = tid >> 6;
    const int l15 = lane & 15, lg = lane >> 4;
    const int mt = wave >> 1, nt = wave & 1;

    const size_t rowbase = ((size_t)b * 1024 + w) * 2048 + (size_t)nh * 256;

    // stage V transposed: vt[c][hk]
    for (int i = 0; i < 32; ++i) {
        int e = i * 256 + tid;
        int hk = e >> 8, c = e & 255;
        vt[c * 40 + hk] = V[rowbase + (size_t)hk * 65536 + c];
    }

    f32x4 sacc = {}, e0 = {}, e1 = {};
#pragma unroll
    for (int k8 = 0; k8 < 256; k8 += 32) {
        bf16x8 af = *(const bf16x8*)&Q[rowbase + (size_t)(mt * 16 + l15) * 65536 + k8 + lg * 8];
        bf16x8 bf = *(const bf16x8*)&K[rowbase + (size_t)(nt * 16 + l15) * 65536 + k8 + lg * 8];
        bf16x8 r0 = *(const bf16x8*)&relb[(size_t)(nt * 32 + l15) * 256 + k8 + lg * 8];
        bf16x8 r1 = *(const bf16x8*)&relb[(size_t)(nt * 32 + 16 + l15) * 256 + k8 + lg * 8];
        sacc = MFMA16(af, bf, sacc);
        e0 = MFMA16(af, r0, e0);
        e1 = MFMA16(af, r1, e1);
    }
#pragma unroll
    for (int r = 0; r < 4; ++r) {
        int row = mt * 16 + lg * 4 + r;
        ssc[row * 32 + nt * 16 + l15] = sacc[r];
        es[row * 64 + nt * 32 + l15] = e0[r];
        es[row * 64 + nt * 32 + 16 + l15] = e1[r];
    }
    __syncthreads();

    {
        int h = tid >> 3, sub = tid & 7;
        float v4[4];
        float mx = -1e30f;
#pragma unroll
        for (int i = 0; i < 4; ++i) {
            int k = sub * 4 + i;
            int dh = k - h; if (dh < 0) dh += 63;
            int dw = k - w; if (dw < 0) dw += 63;
            float s = (ssc[h * 32 + k] + es[h * 64 + dh] + es[h * 64 + dw]) * 0.0625f;
            v4[i] = s;
            mx = fmaxf(mx, s);
        }
        mx = fmaxf(mx, __shfl_xor(mx, 1));
        mx = fmaxf(mx, __shfl_xor(mx, 2));
        mx = fmaxf(mx, __shfl_xor(mx, 4));
        float sum = 0.f;
#pragma unroll
        for (int i = 0; i < 4; ++i) {
            v4[i] = __expf(v4[i] - mx);
            sum += v4[i];
        }
        sum += __shfl_xor(sum, 1);
        sum += __shfl_xor(sum, 2);
        sum += __shfl_xor(sum, 4);
        float inv = 1.f / sum;
#pragma unroll
        for (int i = 0; i < 4; ++i) ps[h * 32 + sub * 4 + i] = __float2bfloat16(v4[i] * inv);
    }
    __syncthreads();

    bf16x8 paf = *(const bf16x8*)&ps[(mt * 16 + l15) * 32 + lg * 8];
#pragma unroll
    for (int j = 0; j < 8; ++j) {
        int ct = nt * 8 + j;  // 0..15
        bf16x8 bv = *(const bf16x8*)&vt[(size_t)(ct * 16 + l15) * 40 + lg * 8];
        f32x4 oacc = {};
        oacc = MFMA16(paf, bv, oacc);
#pragma unroll
        for (int r = 0; r < 4; ++r) {
            int hh = mt * 16 + lg * 4 + r;
            O[rowbase + (size_t)hh * 65536 + ct * 16 + l15] = __float2bfloat16(oacc[r]);
        }
    }
}

// ---------------------------------------------------------------------------
extern "C" void kernel_launch(void* const* d_in, const int* in_sizes, int n_in, void* d_out,
                              int out_size, void* d_ws, size_t ws_size, hipStream_t stream) {
    const float* Xl = (const float*)d_in[0];
    const float* Xr = (const float*)d_in[1];
    const float* Wq = (const float*)d_in[2];
    const float* bq = (const float*)d_in[3];
    const float* Wk = (const float*)d_in[4];
    const float* bk = (const float*)d_in[5];
    const float* Wv = (const float*)d_in[6];
    const float* bv = (const float*)d_in[7];
    const float* Wo = (const float*)d_in[8];
    const float* bo = (const float*)d_in[9];
    const float* rel = (const float*)d_in[10];
    float* out = (float*)d_out;

    char* ws = (char*)d_ws;
    size_t off = 0;
    auto nxt = [&](size_t bytes) {
        void* p = ws + off;
        off += bytes;
        return p;
    };
    __hip_bfloat16* Xbl = (__hip_bfloat16*)nxt(16777216);
    __hip_bfloat16* Xbr = (__hip_bfloat16*)nxt(16777216);
    __hip_bfloat16* Wtq = (__hip_bfloat16*)nxt(8388608);
    __hip_bfloat16* Wtk = (__hip_bfloat16*)nxt(8388608);
    __hip_bfloat16* Wtv = (__hip_bfloat16*)nxt(8388608);
    __hip_bfloat16* Wto = (__hip_bfloat16*)nxt(8388608);
    __hip_bfloat16* relb = (__hip_bfloat16*)nxt(32768);
    __hip_bfloat16* Ql = (__hip_bfloat16*)nxt(16777216);
    __hip_bfloat16* Kl = (__hip_bfloat16*)nxt(16777216);
    __hip_bfloat16* Vl = (__hip_bfloat16*)nxt(16777216);
    __hip_bfloat16* Qr = (__hip_bfloat16*)nxt(16777216);
    __hip_bfloat16* Kr = (__hip_bfloat16*)nxt(16777216);
    __hip_bfloat16* Vr = (__hip_bfloat16*)nxt(16777216);
    // att outputs alias the Xb buffers (Xb dead after phase-1 GEMM)
    __hip_bfloat16* At0 = Xbl;
    __hip_bfloat16* At1 = Xbr;

    dim3 tb(32, 8);
    // X transposes also emit the raw-feature fp32 copy into the concat output
    transpose_x<<<dim3(32, 64, 4), tb, 0, stream>>>(Xl, Xbl, out);
    transpose_x<<<dim3(32, 64, 4), tb, 0, stream>>>(Xr, Xbr, out + 16777216);
    TArgs tw;
    tw.src[0] = Wq; tw.src[1] = Wk; tw.src[2] = Wv; tw.src[3] = Wo;
    tw.dst[0] = Wtq; tw.dst[1] = Wtk; tw.dst[2] = Wtv; tw.dst[3] = Wto;
    transpose_w4<<<dim3(64, 64, 4), tb, 0, stream>>>(tw);
    conv_rel<<<64, 256, 0, stream>>>(rel, relb);

    GArgs g1 = {};
    g1.A[0] = Xbl; g1.A[1] = Xbl; g1.A[2] = Xbl;
    g1.A[3] = Xbr; g1.A[4] = Xbr; g1.A[5] = Xbr;
    g1.B[0] = Wtq; g1.B[1] = Wtk; g1.B[2] = Wtv;
    g1.B[3] = Wtq; g1.B[4] = Wtk; g1.B[5] = Wtv;
    g1.C[0] = Ql; g1.C[1] = Kl; g1.C[2] = Vl;
    g1.C[3] = Qr; g1.C[4] = Kr; g1.C[5] = Vr;
    g1.bias[0] = bq; g1.bias[1] = bk; g1.bias[2] = bv;
    g1.bias[3] = bq; g1.bias[4] = bk; g1.bias[5] = bv;
    // M=4096 (16 m-tiles), N=2048 (8 n-tiles), z=6 -> 768 blocks
    gemm8p<0><<<dim3(8, 16, 6), 512, 0, stream>>>(g1, 2048, 2048, nullptr);

    // dir0: weighted_r = attn(Q_l, K_r, V_r); dir1: weighted_l = attn(Q_r, K_l, V_l)
    attn_kernel<<<dim3(32, 8, 8), 256, 0, stream>>>(Ql, Kr, Vr, Qr, Kl, Vl, relb, At0, At1);

    // phase-2: operands swapped (A=Wo^T rows=n 2048, B=att rows=m 4096)
    GArgs g2 = {};
    g2.A[0] = Wto; g2.A[1] = Wto;
    g2.B[0] = At0; g2.B[1] = At1;
    g2.bias[0] = bo; g2.bias[1] = bo;
    gemm8p<1><<<dim3(16, 8, 2), 512, 0, stream>>>(g2, 2048, 2048, out);
}